// Round 13
// baseline (236.363 us; speedup 1.0000x reference)
//
#include <hip/hip_runtime.h>

// Problem constants
constexpr int Bn = 16, Cd = 256, Hn = 64, Wn = 64, Kc = 1024;
constexpr int QUANT_ELEMS = Bn * Hn * Wn * Cd;   // 16777216
constexpr int LOSS_OFF = QUANT_ELEMS;            // +0 codebook_loss, +1 commitment_loss
constexpr int IDX_OFF = QUANT_ELEMS + 2;         // 65536 indices (stored as float)

typedef _Float16 half8 __attribute__((ext_vector_type(8)));
typedef float f32x4 __attribute__((ext_vector_type(4)));

// ws layout (bytes):
constexpr size_t WS_CBFH = 0;                    // 512 KB fp16 hi codebook (B-frag)
constexpr size_t WS_CBFL = 512 * 1024;           // 512 KB fp16 lo residual
constexpr size_t WS_C2   = 1024 * 1024;          // 4 KB

// Gap threshold (in d-space) for exact full rescan. 3-term error sigma ~1e-5.
constexpr float THR = 1e-4f;

static __device__ __forceinline__ float med3f(float a, float b, float c) {
#if __has_builtin(__builtin_amdgcn_fmed3f)
    return __builtin_amdgcn_fmed3f(a, b, c);
#else
    return fmaxf(fminf(a, b), fminf(fmaxf(a, b), c));
#endif
}

// ---------------------------------------------------------------------------
// Prep: 512 blocks, one (ntile,kblk) fragment unit each. c2 on kblk==0 blocks.
__global__ __launch_bounds__(512) void prep(const float* __restrict__ cb,
                                            _Float16* __restrict__ cbFh,
                                            _Float16* __restrict__ cbFl,
                                            float* __restrict__ c2,
                                            float* __restrict__ out) {
    const int tid = threadIdx.x;
    const int unit = blockIdx.x;          // 512 units = 64 ntiles x 8 kblk
    const int ntile = unit >> 3, kblk = unit & 7;
    const int code_r = tid >> 5;          // 0..15
    const int cc = tid & 31;              // 0..31 (c within kblk slice)
    const float v = cb[(size_t)(ntile * 16 + code_r) * Cd + kblk * 32 + cc];
    const _Float16 hh = (_Float16)v;
    const _Float16 ll = (_Float16)(v - (float)hh);
    const int l = ((cc >> 3) << 4) | code_r;   // lane within fragment
    const int j = cc & 7;
    const size_t e = (size_t)(ntile * 8 + kblk) * 64 + l;
    cbFh[e * 8 + j] = hh;
    cbFl[e * 8 + j] = ll;
    if (kblk == 0) {   // c2 for this ntile's 16 codes (32 parts x 8 c)
        const int i = tid >> 5, part = tid & 31;
        const float* row = cb + (size_t)(ntile * 16 + i) * Cd;
        float s = 0.f;
        #pragma unroll
        for (int c0 = 0; c0 < 8; ++c0) { const float vv = row[part * 8 + c0]; s += vv * vv; }
        s += __shfl_xor(s, 1);
        s += __shfl_xor(s, 2);
        s += __shfl_xor(s, 4);
        s += __shfl_xor(s, 8);
        s += __shfl_xor(s, 16);
        if (part == 0) c2[ntile * 16 + i] = s;
    }
    if (unit == 0 && tid == 0) { out[LOSS_OFF] = 0.f; out[LOSS_OFF + 1] = 0.f; }
}

// ---------------------------------------------------------------------------
// Main MFMA kernel v16 = v15 (3-term, 127us plateau) + two VALU cuts:
//  - grp x kblk FULLY unrolled: ntile/nk compile-time -> B addresses become
//    base + immediate, killing per-step address recompute (~1800 cyc/wave).
//  - c2 folded into acc init (acc = -c2/2): argmin d == argmax acc; fold
//    works in max-space with no per-element fmaf. Gap = 2*(a1-a2) vs THR.
// All comparisons mirrored; tie semantics preserved (strict-improve keeps
// first/lowest code; true ties -> gap 0 -> flagged -> exact rescan).
// Spill gate: FETCH ~47MB / WRITE ~66MB must hold.
__global__ __launch_bounds__(512, 4) void vq_main(const float* __restrict__ x,
                                                  const _Float16* __restrict__ cbFh,
                                                  const _Float16* __restrict__ cbFl,
                                                  const float* __restrict__ c2,
                                                  const float* __restrict__ cb,
                                                  float* __restrict__ out) {
    __shared__ half8 Axh[2048];   // 32 KB: [kblk 8][mt 4][lane 64]
    __shared__ half8 Axl[2048];   // 32 KB
    __shared__ float q1ds[8][32];
    __shared__ int   q1is[8][32];
    __shared__ float q2ds[8][32];
    __shared__ int   idx_s[64];
    __shared__ float red[8];
    __shared__ int   flg[64];     // flagged row ids
    __shared__ int   nflag;
    __shared__ float scan_xs[256];   // exact x row for full rescan
    __shared__ float scan_d[8];
    __shared__ int   scan_k[8];

    const int tid = threadIdx.x;
    const int lane = tid & 63;
    const int wv = tid >> 6;          // 0..7
    const int mth = wv & 1;           // m-half: rows [mth*32, mth*32+32)
    const int ntq = wv >> 1;          // n-quarter: ntiles [ntq*16, ntq*16+16)
    const int bh = blockIdx.x;
    const int b = bh >> 6, h = bh & 63;

    if (tid == 0) nflag = 0;

    // ---- Stage x-tile once: gather + fp16 hi/lo split + lane-contiguous writes
    {
        const int m = tid & 15;           // row within m-tile
        const int q = (tid >> 4) & 3;     // k-quad
        const int mtg = (tid >> 6) & 3;   // m-tile
        const int kh = tid >> 8;          // kblk-half (0/1)
        const int w = mtg * 16 + m;
        const float* xb = x + ((size_t)b * Cd * Hn + h) * Wn + w;   // + c*4096
        #pragma unroll
        for (int kk = 0; kk < 4; ++kk) {
            const int kblk = kh * 4 + kk;
            half8 hv, lv;
            #pragma unroll
            for (int j = 0; j < 8; ++j) {
                const int c = kblk * 32 + q * 8 + j;
                const float v = xb[(size_t)c * (Hn * Wn)];
                const _Float16 hh = (_Float16)v;
                hv[j] = hh;
                lv[j] = (_Float16)(v - (float)hh);
            }
            const int e = (kblk * 4 + mtg) * 64 + (q * 16 + m);   // == ...*64 + lane
            Axh[e] = hv;
            Axl[e] = lv;
        }
    }
    __syncthreads();

    // top-2 state in MAX-space (a = dot - c2/2; larger = closer)
    float q1a[8], q2a[8];
    int   q1i[8];
    #pragma unroll
    for (int i = 0; i < 8; ++i) { q1a[i] = -3.4e38f; q2a[i] = -3.4e38f; q1i[i] = 0; }

    // per-wave B base (halves): be = ntile*4096 + nk*512 + lane*8
    const _Float16* __restrict__ bh_base = cbFh + (size_t)ntq * 65536 + lane * 8;
    const _Float16* __restrict__ bl_base = cbFl + (size_t)ntq * 65536 + lane * 8;

    // B-fragment prefetch slots (1-deep software pipeline); step 0 preload
    half8 nbh[2], nbl[2];
    nbh[0] = *(const half8*)(bh_base + 0);
    nbh[1] = *(const half8*)(bh_base + 4096);
    nbl[0] = *(const half8*)(bl_base + 0);
    nbl[1] = *(const half8*)(bl_base + 4096);

    #pragma unroll
    for (int grp = 0; grp < 8; ++grp) {   // FULL unroll: all offsets immediate
        // c2 for this grp's two code-columns, folded into acc init
        const float c2v0 = c2[(ntq * 16 + grp * 2) * 16 + (lane & 15)];
        const float c2v1 = c2[(ntq * 16 + grp * 2 + 1) * 16 + (lane & 15)];
        const float i0 = -0.5f * c2v0, i1 = -0.5f * c2v1;
        f32x4 acc[2][2];   // [ml][nt]
        acc[0][0] = (f32x4){i0, i0, i0, i0};
        acc[0][1] = (f32x4){i1, i1, i1, i1};
        acc[1][0] = (f32x4){i0, i0, i0, i0};
        acc[1][1] = (f32x4){i1, i1, i1, i1};

        #pragma unroll
        for (int kblk = 0; kblk < 8; ++kblk) {   // FULL unroll
            // consume current slot
            const half8 cbh0 = nbh[0], cbh1 = nbh[1];
            const half8 cbl0 = nbl[0], cbl1 = nbl[1];
            // issue next-step loads (compile-time offsets; wraps at the end)
            {
                const int s = grp * 8 + kblk + 1;
                const int ng = (s >> 3) & 7, nk = s & 7;
                const size_t o0 = (size_t)(ng * 2) * 4096 + nk * 512;
                const size_t o1 = o0 + 4096;
                nbh[0] = *(const half8*)(bh_base + o0);
                nbh[1] = *(const half8*)(bh_base + o1);
                nbl[0] = *(const half8*)(bl_base + o0);
                nbl[1] = *(const half8*)(bl_base + o1);
            }
            half8 ahf[2], alf[2];
            #pragma unroll
            for (int ml = 0; ml < 2; ++ml) {
                const int e = (kblk * 4 + mth * 2 + ml) * 64 + lane;
                ahf[ml] = Axh[e];
                alf[ml] = Axl[e];
            }
            // 3 terms: xh*ch + xh*cl + xl*ch  (= x*c minus tiny xl*cl)
            __builtin_amdgcn_s_setprio(1);
            #pragma unroll
            for (int ml = 0; ml < 2; ++ml) {
                acc[ml][0] = __builtin_amdgcn_mfma_f32_16x16x32_f16(ahf[ml], cbh0, acc[ml][0], 0, 0, 0);
                acc[ml][1] = __builtin_amdgcn_mfma_f32_16x16x32_f16(ahf[ml], cbh1, acc[ml][1], 0, 0, 0);
            }
            #pragma unroll
            for (int ml = 0; ml < 2; ++ml) {
                acc[ml][0] = __builtin_amdgcn_mfma_f32_16x16x32_f16(ahf[ml], cbl0, acc[ml][0], 0, 0, 0);
                acc[ml][1] = __builtin_amdgcn_mfma_f32_16x16x32_f16(ahf[ml], cbl1, acc[ml][1], 0, 0, 0);
            }
            #pragma unroll
            for (int ml = 0; ml < 2; ++ml) {
                acc[ml][0] = __builtin_amdgcn_mfma_f32_16x16x32_f16(alf[ml], cbh0, acc[ml][0], 0, 0, 0);
                acc[ml][1] = __builtin_amdgcn_mfma_f32_16x16x32_f16(alf[ml], cbh1, acc[ml][1], 0, 0, 0);
            }
            __builtin_amdgcn_s_setprio(0);
        }

        // fold this group's 32 codes: top-2 MAX of acc, no per-element fmaf
        #pragma unroll
        for (int nt = 0; nt < 2; ++nt) {
            const int code = (ntq * 16 + grp * 2 + nt) * 16 + (lane & 15);
            #pragma unroll
            for (int ml = 0; ml < 2; ++ml) {
                #pragma unroll
                for (int reg = 0; reg < 4; ++reg) {
                    const float a = acc[ml][nt][reg];
                    const int qi = ml * 4 + reg;
                    q2a[qi] = med3f(q1a[qi], q2a[qi], a);
                    q1i[qi] = (a > q1a[qi]) ? code : q1i[qi];
                    q1a[qi] = fmaxf(q1a[qi], a);
                }
            }
        }
    }

    // cross-lane top-2 merge (max-space) over the 16 code-columns (lane&15)
    #pragma unroll
    for (int off = 1; off < 16; off <<= 1) {
        #pragma unroll
        for (int qi = 0; qi < 8; ++qi) {
            const float oa1 = __shfl_xor(q1a[qi], off);
            const int   oi1 = __shfl_xor(q1i[qi], off);
            const float oa2 = __shfl_xor(q2a[qi], off);
            const float lo = fminf(q1a[qi], oa1);   // loser of the two firsts
            q2a[qi] = fmaxf(fmaxf(q2a[qi], oa2), lo);
            q1i[qi] = (oa1 > q1a[qi]) ? oi1 : q1i[qi];
            q1a[qi] = fmaxf(q1a[qi], oa1);
        }
    }
    if ((lane & 15) == 0) {
        #pragma unroll
        for (int qi = 0; qi < 8; ++qi) {
            const int ml = qi >> 2, reg = qi & 3;
            const int rl = ml * 16 + (lane >> 4) * 4 + reg;   // row within half (0..31)
            q1ds[wv][rl] = q1a[qi];
            q1is[wv][rl] = q1i[qi];
            q2ds[wv][rl] = q2a[qi];
        }
    }
    __syncthreads();
    if (tid < 64) {
        // row tid: half hh covered by waves {hh, hh+2, hh+4, hh+6} (code-ascending)
        const int hh = tid >> 5, rl = tid & 31;
        float a1 = q1ds[hh][rl]; int i1 = q1is[hh][rl]; float a2 = q2ds[hh][rl];
        #pragma unroll
        for (int v = 1; v < 4; ++v) {
            const int w2 = hh + 2 * v;
            const float oa1 = q1ds[w2][rl]; const int oi1 = q1is[w2][rl];
            const float oa2 = q2ds[w2][rl];
            const float lo = fminf(a1, oa1);
            a2 = fmaxf(fmaxf(a2, oa2), lo);
            i1 = (oa1 > a1) ? oi1 : i1;
            a1 = fmaxf(a1, oa1);
        }
        idx_s[tid] = i1;
        // d-space gap = 2*(a1 - a2)
        if (2.0f * (a1 - a2) < THR) {        // tight gap -> exact full rescan
            const int pos = atomicAdd(&nflag, 1);
            flg[pos] = tid;
        }
    }
    __syncthreads();

    // ---- Exact full 1024-code rescan of flagged rows (expected ~0 per block).
    // Exact x from LDS (xh+xl, err ~2^-24); d = c2 - 2*dot fp32; tie -> lowest k.
    const int nf = nflag;
    for (int fi = 0; fi < nf; ++fi) {
        const int wrow = flg[fi];
        if (tid < 256) {
            const int c = tid;
            const int mt = wrow >> 4, m = wrow & 15;
            const int e = ((c >> 5) * 4 + mt) * 64 + ((c >> 3) & 3) * 16 + m;
            const int j = c & 7;
            scan_xs[c] = (float)Axh[e][j] + (float)Axl[e][j];
        }
        __syncthreads();
        float bd = 3.4e38f; int bk = 0;
        #pragma unroll
        for (int r = 0; r < 2; ++r) {
            const int code = tid * 2 + r;
            const float4* cr = (const float4*)(cb + (size_t)code * Cd);
            const float4* xr = (const float4*)scan_xs;
            float dot = 0.f;
            #pragma unroll 8
            for (int i = 0; i < 64; ++i) {
                const float4 v = cr[i];
                const float4 xv = xr[i];
                dot = fmaf(v.x, xv.x, dot);
                dot = fmaf(v.y, xv.y, dot);
                dot = fmaf(v.z, xv.z, dot);
                dot = fmaf(v.w, xv.w, dot);
            }
            const float d = c2[code] - 2.f * dot;
            if (d < bd || (d == bd && code < bk)) { bd = d; bk = code; }
        }
        #pragma unroll
        for (int off = 32; off >= 1; off >>= 1) {
            const float od = __shfl_xor(bd, off);
            const int   ok = __shfl_xor(bk, off);
            if (od < bd || (od == bd && ok < bk)) { bd = od; bk = ok; }
        }
        if (lane == 0) { scan_d[wv] = bd; scan_k[wv] = bk; }
        __syncthreads();
        if (tid == 0) {
            float fd = scan_d[0]; int fk = scan_k[0];
            #pragma unroll
            for (int v = 1; v < 8; ++v) {
                const float od = scan_d[v]; const int ok = scan_k[v];
                if (od < fd || (od == fd && ok < fk)) { fd = od; fk = ok; }
            }
            idx_s[wrow] = fk;
        }
        __syncthreads();
    }

    // indices out (post-rescan)
    if (tid < 64) out[IDX_OFF + bh * 64 + tid] = (float)idx_s[tid];

    // ---- Fused epilogue: quant gather (L2-resident cb), coalesced writes,
    //      loss from LDS-reconstructed x (xh+xl, error ~2^-24).
    {
        const int w = tid & 63;           // row
        const int kblk = wv;              // c-eighth: c in [wv*32, wv*32+32)
        const int m = w & 15, mt = w >> 4;
        const int myidx = idx_s[w];
        const float4* cbrow = (const float4*)(cb + (size_t)myidx * Cd + kblk * 32);
        float lsum = 0.f;
        #pragma unroll
        for (int q = 0; q < 4; ++q) {
            const int e = (kblk * 4 + mt) * 64 + q * 16 + m;
            const half8 hv = Axh[e];
            const half8 lv = Axl[e];
            const float4 qa = cbrow[q * 2];
            const float4 qb = cbrow[q * 2 + 1];
            const float qv[8] = {qa.x, qa.y, qa.z, qa.w, qb.x, qb.y, qb.z, qb.w};
            const int cbase = kblk * 32 + q * 8;
            #pragma unroll
            for (int j = 0; j < 8; ++j) {
                const float xv = (float)hv[j] + (float)lv[j];
                const float dd = qv[j] - xv;
                lsum += dd * dd;
                out[(((size_t)b * Cd + cbase + j) * Hn + h) * Wn + w] = qv[j];
            }
        }
        #pragma unroll
        for (int off = 32; off >= 1; off >>= 1) lsum += __shfl_xor(lsum, off);
        if (lane == 0) red[wv] = lsum;
    }
    __syncthreads();
    if (tid == 0) {
        float s = 0.f;
        #pragma unroll
        for (int i = 0; i < 8; ++i) s += red[i];
        s *= (1.0f / 16777216.0f);
        atomicAdd(out + LOSS_OFF, s);
        atomicAdd(out + LOSS_OFF + 1, s);
    }
}

// ---------------------------------------------------------------------------
extern "C" void kernel_launch(void* const* d_in, const int* in_sizes, int n_in,
                              void* d_out, int out_size, void* d_ws, size_t ws_size,
                              hipStream_t stream) {
    const float* x  = (const float*)d_in[0];   // (16,256,64,64)
    const float* cb = (const float*)d_in[1];   // (1024,256)
    float* out = (float*)d_out;
    char* ws = (char*)d_ws;
    _Float16* cbFh = (_Float16*)(ws + WS_CBFH);
    _Float16* cbFl = (_Float16*)(ws + WS_CBFL);
    float* c2      = (float*)(ws + WS_C2);

    prep<<<512, 512, 0, stream>>>(cb, cbFh, cbFl, c2, out);
    vq_main<<<Bn * Hn, 512, 0, stream>>>(x, cbFh, cbFl, c2, cb, out);
}

// Round 14
// 213.502 us; speedup vs baseline: 1.1071x; 1.1071x over previous
//
#include <hip/hip_runtime.h>

// Problem constants
constexpr int Bn = 16, Cd = 256, Hn = 64, Wn = 64, Kc = 1024;
constexpr int QUANT_ELEMS = Bn * Hn * Wn * Cd;   // 16777216
constexpr int LOSS_OFF = QUANT_ELEMS;            // +0 codebook_loss, +1 commitment_loss
constexpr int IDX_OFF = QUANT_ELEMS + 2;         // 65536 indices (stored as float)

typedef _Float16 half8 __attribute__((ext_vector_type(8)));
typedef float f32x4 __attribute__((ext_vector_type(4)));

// ws layout (bytes):
constexpr size_t WS_CBFH = 0;                    // 512 KB fp16 hi codebook (B-frag)
constexpr size_t WS_CBFL = 512 * 1024;           // 512 KB fp16 lo residual
constexpr size_t WS_C2   = 1024 * 1024;          // 4 KB

// Gap threshold for exact full rescan (3-term error sigma ~1e-5 -> ~0 flags).
// v14 lesson: 2-term + THR=0.12 flags ~5-10% of rows -> rescan stragglers
// cost +200us. The 3rd MFMA term's 19us buys a ~0 flag rate. Keep 3-term.
constexpr float THR = 1e-4f;

static __device__ __forceinline__ float med3f(float a, float b, float c) {
#if __has_builtin(__builtin_amdgcn_fmed3f)
    return __builtin_amdgcn_fmed3f(a, b, c);
#else
    return fmaxf(fminf(a, b), fminf(fmaxf(a, b), c));
#endif
}

// ---------------------------------------------------------------------------
// Prep: 512 blocks, one (ntile,kblk) fragment unit each. c2 on kblk==0 blocks.
__global__ __launch_bounds__(512) void prep(const float* __restrict__ cb,
                                            _Float16* __restrict__ cbFh,
                                            _Float16* __restrict__ cbFl,
                                            float* __restrict__ c2,
                                            float* __restrict__ out) {
    const int tid = threadIdx.x;
    const int unit = blockIdx.x;          // 512 units = 64 ntiles x 8 kblk
    const int ntile = unit >> 3, kblk = unit & 7;
    const int code_r = tid >> 5;          // 0..15
    const int cc = tid & 31;              // 0..31 (c within kblk slice)
    const float v = cb[(size_t)(ntile * 16 + code_r) * Cd + kblk * 32 + cc];
    const _Float16 hh = (_Float16)v;
    const _Float16 ll = (_Float16)(v - (float)hh);
    const int l = ((cc >> 3) << 4) | code_r;   // lane within fragment
    const int j = cc & 7;
    const size_t e = (size_t)(ntile * 8 + kblk) * 64 + l;
    cbFh[e * 8 + j] = hh;
    cbFl[e * 8 + j] = ll;
    if (kblk == 0) {   // c2 for this ntile's 16 codes (32 parts x 8 c)
        const int i = tid >> 5, part = tid & 31;
        const float* row = cb + (size_t)(ntile * 16 + i) * Cd;
        float s = 0.f;
        #pragma unroll
        for (int c0 = 0; c0 < 8; ++c0) { const float vv = row[part * 8 + c0]; s += vv * vv; }
        s += __shfl_xor(s, 1);
        s += __shfl_xor(s, 2);
        s += __shfl_xor(s, 4);
        s += __shfl_xor(s, 8);
        s += __shfl_xor(s, 16);
        if (part == 0) c2[ntile * 16 + i] = s;
    }
    if (unit == 0 && tid == 0) { out[LOSS_OFF] = 0.f; out[LOSS_OFF + 1] = 0.f; }
}

// ---------------------------------------------------------------------------
// Main MFMA kernel v17 = v15 verbatim (best verified: 213.99 us total,
// vq_main ~127 us, VGPR 64, no scratch). v16's full-unroll VALU cut spilled
// (FETCH 47->94, WRITE 66->152 MB) and is rejected. Session conclusion:
// this structure's plateau is latency-bound at ~72% combined MFMA+VALU
// issue; deeper ILP is blocked by the ~64-arch-VGPR spill cliff at 512x4
// launch bounds, and lower-occupancy/higher-reg configs measured worse
// (v5/v7). 3-term split-fp16 MFMA + ~0-rate exact-rescan safety net is the
// verified numerics optimum (v14 falsified 2-term).
__global__ __launch_bounds__(512, 4) void vq_main(const float* __restrict__ x,
                                                  const _Float16* __restrict__ cbFh,
                                                  const _Float16* __restrict__ cbFl,
                                                  const float* __restrict__ c2,
                                                  const float* __restrict__ cb,
                                                  float* __restrict__ out) {
    __shared__ half8 Axh[2048];   // 32 KB: [kblk 8][mt 4][lane 64]
    __shared__ half8 Axl[2048];   // 32 KB
    __shared__ float q1ds[8][32];
    __shared__ int   q1is[8][32];
    __shared__ float q2ds[8][32];
    __shared__ int   idx_s[64];
    __shared__ float red[8];
    __shared__ int   flg[64];     // flagged row ids
    __shared__ int   nflag;
    __shared__ float scan_xs[256];   // exact x row for full rescan
    __shared__ float scan_d[8];
    __shared__ int   scan_k[8];

    const int tid = threadIdx.x;
    const int lane = tid & 63;
    const int wv = tid >> 6;          // 0..7
    const int mth = wv & 1;           // m-half: rows [mth*32, mth*32+32)
    const int ntq = wv >> 1;          // n-quarter: ntiles [ntq*16, ntq*16+16)
    const int bh = blockIdx.x;
    const int b = bh >> 6, h = bh & 63;

    if (tid == 0) nflag = 0;

    // ---- Stage x-tile once: gather + fp16 hi/lo split + lane-contiguous writes
    {
        const int m = tid & 15;           // row within m-tile
        const int q = (tid >> 4) & 3;     // k-quad
        const int mtg = (tid >> 6) & 3;   // m-tile
        const int kh = tid >> 8;          // kblk-half (0/1)
        const int w = mtg * 16 + m;
        const float* xb = x + ((size_t)b * Cd * Hn + h) * Wn + w;   // + c*4096
        #pragma unroll
        for (int kk = 0; kk < 4; ++kk) {
            const int kblk = kh * 4 + kk;
            half8 hv, lv;
            #pragma unroll
            for (int j = 0; j < 8; ++j) {
                const int c = kblk * 32 + q * 8 + j;
                const float v = xb[(size_t)c * (Hn * Wn)];
                const _Float16 hh = (_Float16)v;
                hv[j] = hh;
                lv[j] = (_Float16)(v - (float)hh);
            }
            const int e = (kblk * 4 + mtg) * 64 + (q * 16 + m);   // == ...*64 + lane
            Axh[e] = hv;
            Axl[e] = lv;
        }
    }
    __syncthreads();

    float q1d[8], q2d[8];
    int   q1i[8];
    #pragma unroll
    for (int i = 0; i < 8; ++i) { q1d[i] = 3.4e38f; q2d[i] = 3.4e38f; q1i[i] = 0; }

    // B-fragment prefetch slots (1-deep software pipeline)
    half8 nbh[2], nbl[2];
    #pragma unroll
    for (int nt = 0; nt < 2; ++nt) {
        const int ntile = ntq * 16 + nt;
        const size_t be = ((size_t)(ntile * 8) * 64 + lane) * 8;
        nbh[nt] = *(const half8*)(cbFh + be);
        nbl[nt] = *(const half8*)(cbFl + be);
    }

    #pragma unroll 2
    for (int grp = 0; grp < 8; ++grp) {   // 2 n-tiles per group; unroll 2 so
        f32x4 acc[2][2];   // [ml][nt]       fold(g) overlaps MFMA(g+1)
        acc[0][0] = (f32x4){0.f, 0.f, 0.f, 0.f};
        acc[0][1] = (f32x4){0.f, 0.f, 0.f, 0.f};
        acc[1][0] = (f32x4){0.f, 0.f, 0.f, 0.f};
        acc[1][1] = (f32x4){0.f, 0.f, 0.f, 0.f};

        #pragma unroll 2
        for (int kblk = 0; kblk < 8; ++kblk) {
            // consume current slot
            const half8 cbh0 = nbh[0], cbh1 = nbh[1];
            const half8 cbl0 = nbl[0], cbl1 = nbl[1];
            // issue next-iteration loads (wraps harmlessly at the very end)
            {
                const int nk = (kblk + 1) & 7;
                const int ng = (grp + ((kblk + 1) >> 3)) & 7;
                #pragma unroll
                for (int nt = 0; nt < 2; ++nt) {
                    const int ntile = ntq * 16 + ng * 2 + nt;
                    const size_t be = ((size_t)(ntile * 8 + nk) * 64 + lane) * 8;
                    nbh[nt] = *(const half8*)(cbFh + be);
                    nbl[nt] = *(const half8*)(cbFl + be);
                }
            }
            half8 ahf[2], alf[2];
            #pragma unroll
            for (int ml = 0; ml < 2; ++ml) {
                const int e = (kblk * 4 + mth * 2 + ml) * 64 + lane;
                ahf[ml] = Axh[e];
                alf[ml] = Axl[e];
            }
            // 3 terms: xh*ch + xh*cl + xl*ch  (= x*c minus tiny xl*cl)
            __builtin_amdgcn_s_setprio(1);
            #pragma unroll
            for (int ml = 0; ml < 2; ++ml) {
                acc[ml][0] = __builtin_amdgcn_mfma_f32_16x16x32_f16(ahf[ml], cbh0, acc[ml][0], 0, 0, 0);
                acc[ml][1] = __builtin_amdgcn_mfma_f32_16x16x32_f16(ahf[ml], cbh1, acc[ml][1], 0, 0, 0);
            }
            #pragma unroll
            for (int ml = 0; ml < 2; ++ml) {
                acc[ml][0] = __builtin_amdgcn_mfma_f32_16x16x32_f16(ahf[ml], cbl0, acc[ml][0], 0, 0, 0);
                acc[ml][1] = __builtin_amdgcn_mfma_f32_16x16x32_f16(ahf[ml], cbl1, acc[ml][1], 0, 0, 0);
            }
            #pragma unroll
            for (int ml = 0; ml < 2; ++ml) {
                acc[ml][0] = __builtin_amdgcn_mfma_f32_16x16x32_f16(alf[ml], cbh0, acc[ml][0], 0, 0, 0);
                acc[ml][1] = __builtin_amdgcn_mfma_f32_16x16x32_f16(alf[ml], cbh1, acc[ml][1], 0, 0, 0);
            }
            __builtin_amdgcn_s_setprio(0);
        }

        // fold this group's 32 codes into per-row top-2 (lean: med3, no q2i)
        #pragma unroll
        for (int nt = 0; nt < 2; ++nt) {
            const int code = (ntq * 16 + grp * 2 + nt) * 16 + (lane & 15);
            const float c2v = c2[code];
            #pragma unroll
            for (int ml = 0; ml < 2; ++ml) {
                #pragma unroll
                for (int reg = 0; reg < 4; ++reg) {
                    const float d = fmaf(-2.f, acc[ml][nt][reg], c2v);
                    const int qi = ml * 4 + reg;
                    q2d[qi] = med3f(q1d[qi], q2d[qi], d);
                    q1i[qi] = (d < q1d[qi]) ? code : q1i[qi];
                    q1d[qi] = fminf(q1d[qi], d);
                }
            }
        }
    }

    // cross-lane top-2 merge over the 16 code-columns (lane&15)
    #pragma unroll
    for (int off = 1; off < 16; off <<= 1) {
        #pragma unroll
        for (int qi = 0; qi < 8; ++qi) {
            const float od1 = __shfl_xor(q1d[qi], off);
            const int   oi1 = __shfl_xor(q1i[qi], off);
            const float od2 = __shfl_xor(q2d[qi], off);
            const float hi = fmaxf(q1d[qi], od1);
            q2d[qi] = fminf(fminf(q2d[qi], od2), hi);
            q1i[qi] = (od1 < q1d[qi]) ? oi1 : q1i[qi];
            q1d[qi] = fminf(q1d[qi], od1);
        }
    }
    if ((lane & 15) == 0) {
        #pragma unroll
        for (int qi = 0; qi < 8; ++qi) {
            const int ml = qi >> 2, reg = qi & 3;
            const int rl = ml * 16 + (lane >> 4) * 4 + reg;   // row within half (0..31)
            q1ds[wv][rl] = q1d[qi];
            q1is[wv][rl] = q1i[qi];
            q2ds[wv][rl] = q2d[qi];
        }
    }
    __syncthreads();
    if (tid < 64) {
        // row tid: half hh covered by waves {hh, hh+2, hh+4, hh+6} (code-ascending)
        const int hh = tid >> 5, rl = tid & 31;
        float d1 = q1ds[hh][rl]; int i1 = q1is[hh][rl]; float d2 = q2ds[hh][rl];
        #pragma unroll
        for (int v = 1; v < 4; ++v) {
            const int w2 = hh + 2 * v;
            const float od1 = q1ds[w2][rl]; const int oi1 = q1is[w2][rl];
            const float od2 = q2ds[w2][rl];
            const float hi = fmaxf(d1, od1);
            d2 = fminf(fminf(d2, od2), hi);
            i1 = (od1 < d1) ? oi1 : i1;
            d1 = fminf(d1, od1);
        }
        idx_s[tid] = i1;
        if (d2 - d1 < THR) {                 // tight gap -> exact full rescan
            const int pos = atomicAdd(&nflag, 1);
            flg[pos] = tid;
        }
    }
    __syncthreads();

    // ---- Exact full 1024-code rescan of flagged rows (expected ~0 per block).
    // Exact x from LDS (xh+xl, err ~2^-24); d = c2 - 2*dot fp32; tie -> lowest k.
    const int nf = nflag;
    for (int fi = 0; fi < nf; ++fi) {
        const int wrow = flg[fi];
        if (tid < 256) {
            const int c = tid;
            const int mt = wrow >> 4, m = wrow & 15;
            const int e = ((c >> 5) * 4 + mt) * 64 + ((c >> 3) & 3) * 16 + m;
            const int j = c & 7;
            scan_xs[c] = (float)Axh[e][j] + (float)Axl[e][j];
        }
        __syncthreads();
        float bd = 3.4e38f; int bk = 0;
        #pragma unroll
        for (int r = 0; r < 2; ++r) {
            const int code = tid * 2 + r;
            const float4* cr = (const float4*)(cb + (size_t)code * Cd);
            const float4* xr = (const float4*)scan_xs;
            float dot = 0.f;
            #pragma unroll 8
            for (int i = 0; i < 64; ++i) {
                const float4 v = cr[i];
                const float4 xv = xr[i];
                dot = fmaf(v.x, xv.x, dot);
                dot = fmaf(v.y, xv.y, dot);
                dot = fmaf(v.z, xv.z, dot);
                dot = fmaf(v.w, xv.w, dot);
            }
            const float d = c2[code] - 2.f * dot;
            if (d < bd || (d == bd && code < bk)) { bd = d; bk = code; }
        }
        #pragma unroll
        for (int off = 32; off >= 1; off >>= 1) {
            const float od = __shfl_xor(bd, off);
            const int   ok = __shfl_xor(bk, off);
            if (od < bd || (od == bd && ok < bk)) { bd = od; bk = ok; }
        }
        if (lane == 0) { scan_d[wv] = bd; scan_k[wv] = bk; }
        __syncthreads();
        if (tid == 0) {
            float fd = scan_d[0]; int fk = scan_k[0];
            #pragma unroll
            for (int v = 1; v < 8; ++v) {
                const float od = scan_d[v]; const int ok = scan_k[v];
                if (od < fd || (od == fd && ok < fk)) { fd = od; fk = ok; }
            }
            idx_s[wrow] = fk;
        }
        __syncthreads();
    }

    // indices out (post-rescan)
    if (tid < 64) out[IDX_OFF + bh * 64 + tid] = (float)idx_s[tid];

    // ---- Fused epilogue: quant gather (L2-resident cb), coalesced writes,
    //      loss from LDS-reconstructed x (xh+xl, error ~2^-24).
    {
        const int w = tid & 63;           // row
        const int kblk = wv;              // c-eighth: c in [wv*32, wv*32+32)
        const int m = w & 15, mt = w >> 4;
        const int myidx = idx_s[w];
        const float4* cbrow = (const float4*)(cb + (size_t)myidx * Cd + kblk * 32);
        float lsum = 0.f;
        #pragma unroll
        for (int q = 0; q < 4; ++q) {
            const int e = (kblk * 4 + mt) * 64 + q * 16 + m;
            const half8 hv = Axh[e];
            const half8 lv = Axl[e];
            const float4 qa = cbrow[q * 2];
            const float4 qb = cbrow[q * 2 + 1];
            const float qv[8] = {qa.x, qa.y, qa.z, qa.w, qb.x, qb.y, qb.z, qb.w};
            const int cbase = kblk * 32 + q * 8;
            #pragma unroll
            for (int j = 0; j < 8; ++j) {
                const float xv = (float)hv[j] + (float)lv[j];
                const float dd = qv[j] - xv;
                lsum += dd * dd;
                out[(((size_t)b * Cd + cbase + j) * Hn + h) * Wn + w] = qv[j];
            }
        }
        #pragma unroll
        for (int off = 32; off >= 1; off >>= 1) lsum += __shfl_xor(lsum, off);
        if (lane == 0) red[wv] = lsum;
    }
    __syncthreads();
    if (tid == 0) {
        float s = 0.f;
        #pragma unroll
        for (int i = 0; i < 8; ++i) s += red[i];
        s *= (1.0f / 16777216.0f);
        atomicAdd(out + LOSS_OFF, s);
        atomicAdd(out + LOSS_OFF + 1, s);
    }
}

// ---------------------------------------------------------------------------
extern "C" void kernel_launch(void* const* d_in, const int* in_sizes, int n_in,
                              void* d_out, int out_size, void* d_ws, size_t ws_size,
                              hipStream_t stream) {
    const float* x  = (const float*)d_in[0];   // (16,256,64,64)
    const float* cb = (const float*)d_in[1];   // (1024,256)
    float* out = (float*)d_out;
    char* ws = (char*)d_ws;
    _Float16* cbFh = (_Float16*)(ws + WS_CBFH);
    _Float16* cbFl = (_Float16*)(ws + WS_CBFL);
    float* c2      = (float*)(ws + WS_C2);

    prep<<<512, 512, 0, stream>>>(cb, cbFh, cbFl, c2, out);
    vq_main<<<Bn * Hn, 512, 0, stream>>>(x, cbFh, cbFl, c2, cb, out);
}